// Round 1
// baseline (133.003 us; speedup 1.0000x reference)
//
#include <hip/hip_runtime.h>

// Corr1d_x: out[n,ch,h,w] = (1/C) * sum_c img1[n,c,h,w] * img2[n,c,h,w + (ch-23)]
//   (zero where w+ch-23 outside [0,W))
// Shapes: img1,img2 [8,256,128,256] fp32; out [8,27,128,256] fp32.
// Memory-bound: 512MB read + 28MB write -> ~86us floor at 6.3 TB/s.

#define N_      8
#define C_      256
#define H_      128
#define W_      256
#define NCH     27          // 2*13+1 output channels
#define CHUNK   8           // c-slices per barrier
#define NCHUNK  (C_ / CHUNK)
#define LROW    288         // 24 left pad + 256 + 8 right pad (floats)
#define PADL    24

__device__ __forceinline__ void async_cp16(const float* g, float* l) {
  // global -> LDS direct, 16B/lane (wave loads 1KB contiguous)
  __builtin_amdgcn_global_load_lds(
      (const __attribute__((address_space(1))) void*)g,
      (__attribute__((address_space(3))) void*)l,
      16, 0, 0);
}

__global__ __launch_bounds__(128, 2)
void corr1d_kernel(const float* __restrict__ img1,
                   const float* __restrict__ img2,
                   float* __restrict__ out) {
  __shared__ __align__(16) float lds[2][CHUNK][LROW];

  const int tid  = threadIdx.x;      // 0..127
  const int w0   = tid << 1;         // each thread owns outputs w0, w0+1
  const int nh   = blockIdx.x;       // n*H + h
  const int n    = nh >> 7;          // H_ = 128
  const int h    = nh & (H_ - 1);
  const int wave = tid >> 6;         // 0..1
  const int lane = tid & 63;

  // Zero the whole LDS once; pads [0,24) and [280,288) stay zero forever,
  // which implements the shift boundary (reference zero-padding).
  {
    float* p0 = &lds[0][0][0];
    #pragma unroll
    for (int i = 0; i < (2 * CHUNK * LROW) / 128; ++i)
      p0[tid + i * 128] = 0.0f;
  }
  __syncthreads();

  const size_t plane = (size_t)H_ * W_;   // stride between c slices
  const float* i1p = img1 + (size_t)n * C_ * plane + (size_t)h * W_ + w0;
  const float* i2p = img2 + (size_t)n * C_ * plane + (size_t)h * W_ + lane * 4;

  float2 p[CHUNK];        // img1 prefetch (next chunk)
  float2 acc[NCH];
  #pragma unroll
  for (int ch = 0; ch < NCH; ++ch) acc[ch] = make_float2(0.0f, 0.0f);

  auto stage = [&](int c0, int buf) {
    // 8 img2 rows -> LDS; each wave stages 4 rows, 1 instr per 1KB row
    #pragma unroll
    for (int r = 0; r < CHUNK / 2; ++r) {
      const int row = wave * (CHUNK / 2) + r;
      async_cp16(i2p + (size_t)(c0 + row) * plane, &lds[buf][row][PADL]);
    }
  };
  auto pf1 = [&](int c0) {
    #pragma unroll
    for (int r = 0; r < CHUNK; ++r)
      p[r] = *(const float2*)(i1p + (size_t)(c0 + r) * plane);
  };

  stage(0, 0);
  pf1(0);

  for (int k = 0; k < NCHUNK; ++k) {
    const int buf = k & 1;
    __syncthreads();                 // drains vmcnt: chunk k (LDS + img1 regs) ready
    float2 cur[CHUNK];
    #pragma unroll
    for (int r = 0; r < CHUNK; ++r) cur[r] = p[r];
    if (k + 1 < NCHUNK) {            // issue next chunk before computing (overlap)
      stage((k + 1) * CHUNK, buf ^ 1);
      pf1((k + 1) * CHUNK);
    }
    #pragma unroll
    for (int r = 0; r < CHUNK; ++r) {
      const float* lrow = &lds[buf][r][w0];   // slot w0+j == img2[w0 + j - 24]
      float f[30];
      #pragma unroll
      for (int q = 0; q < 15; ++q) {          // aligned float2 reads, slots w0..w0+29
        float2 t = *(const float2*)(lrow + 2 * q);
        f[2 * q] = t.x; f[2 * q + 1] = t.y;
      }
      const float2 a = cur[r];
      #pragma unroll
      for (int ch = 0; ch < NCH; ++ch) {
        // img2[w0   + ch - 23] -> slot w0+ch+1 -> f[ch+1]
        // img2[w0+1 + ch - 23] -> slot w0+ch+2 -> f[ch+2]
        acc[ch].x = fmaf(a.x, f[ch + 1], acc[ch].x);
        acc[ch].y = fmaf(a.y, f[ch + 2], acc[ch].y);
      }
    }
  }

  const float scale = 1.0f / C_;
  float* op = out + (size_t)n * NCH * plane + (size_t)h * W_ + w0;
  #pragma unroll
  for (int ch = 0; ch < NCH; ++ch) {
    float2 v = make_float2(acc[ch].x * scale, acc[ch].y * scale);
    *(float2*)(op + (size_t)ch * plane) = v;
  }
}

extern "C" void kernel_launch(void* const* d_in, const int* in_sizes, int n_in,
                              void* d_out, int out_size, void* d_ws, size_t ws_size,
                              hipStream_t stream) {
  const float* img1 = (const float*)d_in[0];
  const float* img2 = (const float*)d_in[1];
  float* out = (float*)d_out;
  corr1d_kernel<<<dim3(N_ * H_), dim3(128), 0, stream>>>(img1, img2, out);
}